// Round 1
// baseline (382.669 us; speedup 1.0000x reference)
//
#include <hip/hip_runtime.h>
#include <cstdint>
#include <cstddef>

#define B_ 4
#define T_ 8192
#define D_ 2048
#define K_ 4096   // int(0.5*T + 0.5) = 4096

// ---------------- Kernel 1: scores + sortable keys -------------------------
// One wave (64 lanes) per row; block = 256 threads = 4 rows.
// Each lane: 8 float4 loads of h (contiguous 1 KiB per wave-instruction),
// W staged once per block into LDS.
__global__ __launch_bounds__(256) void score_kernel(
    const float* __restrict__ h, const float* __restrict__ W,
    const float* __restrict__ bias, float* __restrict__ scores,
    uint32_t* __restrict__ keys)
{
    __shared__ float4 wlds[D_ / 4];
    const int tid = threadIdx.x;
    const float4* W4 = (const float4*)W;
    #pragma unroll
    for (int i = 0; i < (D_ / 4) / 256; ++i)
        wlds[tid + i * 256] = W4[tid + i * 256];
    __syncthreads();

    const int lane = tid & 63;
    const int wid  = tid >> 6;
    const int row  = blockIdx.x * 4 + wid;

    const float4* h4 = (const float4*)(h + (size_t)row * D_);
    float acc = 0.f;
    #pragma unroll
    for (int j = 0; j < 8; ++j) {
        float4 a = h4[lane + j * 64];
        float4 w = wlds[lane + j * 64];
        acc = fmaf(a.x, w.x, acc);
        acc = fmaf(a.y, w.y, acc);
        acc = fmaf(a.z, w.z, acc);
        acc = fmaf(a.w, w.w, acc);
    }
    #pragma unroll
    for (int off = 32; off > 0; off >>= 1) acc += __shfl_down(acc, off);

    if (lane == 0) {
        float z = acc + bias[0];
        float s = 1.0f / (1.0f + expf(-z));          // precise expf: >0.5 boundary
        scores[row] = s;
        // float -> order-preserving unsigned key (descending top-k == max keys)
        uint32_t u = __float_as_uint(z);
        keys[row] = (u & 0x80000000u) ? ~u : (u | 0x80000000u);
    }
}

// ---------------- Kernel 2: exact k-th largest + mask ----------------------
// One block (1024 threads) per batch row. 8 keys/thread in registers
// (thread t owns contiguous elements [t*8, t*8+8) for stable tie ranking).
__global__ __launch_bounds__(1024) void topk_kernel(
    const uint32_t* __restrict__ keys, const float* __restrict__ scores,
    const unsigned char* __restrict__ exited, float* __restrict__ mask)
{
    const int b    = blockIdx.x;
    const int tid  = threadIdx.x;
    const int lane = tid & 63;
    const int wid  = tid >> 6;

    __shared__ int red[17];

    const uint32_t* krow = keys + (size_t)b * T_;
    uint32_t key[8];
    {
        const uint4* k4 = (const uint4*)(krow + tid * 8);
        uint4 ka = k4[0], kb = k4[1];
        key[0] = ka.x; key[1] = ka.y; key[2] = ka.z; key[3] = ka.w;
        key[4] = kb.x; key[5] = kb.y; key[6] = kb.z; key[7] = kb.w;
    }

    // block-wide count of keys >= thresh (uniform control flow required)
    auto blockCountGE = [&](uint32_t thresh) -> int {
        int c = 0;
        #pragma unroll
        for (int j = 0; j < 8; ++j) c += (key[j] >= thresh) ? 1 : 0;
        #pragma unroll
        for (int off = 32; off > 0; off >>= 1) c += __shfl_down(c, off);
        __syncthreads();                 // protect red[] from previous call
        if (lane == 0) red[wid] = c;
        __syncthreads();
        if (tid == 0) { int t = 0; for (int i = 0; i < 16; ++i) t += red[i]; red[16] = t; }
        __syncthreads();
        return red[16];
    };

    // binary search: largest key value Kstar with count_ge(Kstar) >= K_
    unsigned lo = 0u, hi = 0xFFFFFFFFu;   // invariant: count_ge(lo) >= K_
    while (lo < hi) {                      // lo/hi uniform across the block
        unsigned mid = lo + ((hi - lo) >> 1) + 1u;   // upper mid, no overflow
        int c = blockCountGE(mid);
        if (c >= K_) lo = mid; else hi = mid - 1u;
    }
    const uint32_t Kstar = lo;
    const int cgt = (Kstar == 0xFFFFFFFFu) ? 0 : blockCountGE(Kstar + 1u);
    const int budget = K_ - cgt;          // how many ties (== Kstar) to accept

    // stable tie ranking: exclusive prefix (by index) of (key == Kstar)
    int tieLocal = 0;
    #pragma unroll
    for (int j = 0; j < 8; ++j) tieLocal += (key[j] == Kstar) ? 1 : 0;
    int inc = tieLocal;
    #pragma unroll
    for (int off = 1; off < 64; off <<= 1) {
        int y = __shfl_up(inc, off);
        if (lane >= off) inc += y;
    }
    __syncthreads();
    if (lane == 63) red[wid] = inc;       // wave totals
    __syncthreads();
    if (tid == 0) {
        int run = 0;
        for (int i = 0; i < 16; ++i) { int t = red[i]; red[i] = run; run += t; }
    }
    __syncthreads();
    int tieOff = red[wid] + (inc - tieLocal);   // my exclusive tie rank

    const float* srow = scores + (size_t)b * T_;
    const unsigned char* erow = exited + (size_t)b * T_;
    float out[8];
    #pragma unroll
    for (int j = 0; j < 8; ++j) {
        const int t = tid * 8 + j;
        bool sel;
        if (key[j] > Kstar)        sel = true;
        else if (key[j] == Kstar)  { sel = (tieOff < budget); ++tieOff; }
        else                       sel = false;
        sel = sel && (srow[t] > 0.5f) && (erow[t] == 0);
        out[j] = sel ? 1.0f : 0.0f;
    }
    float4* m4 = (float4*)(mask + (size_t)b * T_ + tid * 8);
    m4[0] = make_float4(out[0], out[1], out[2], out[3]);
    m4[1] = make_float4(out[4], out[5], out[6], out[7]);
}

// ---------------------------------------------------------------------------
extern "C" void kernel_launch(void* const* d_in, const int* in_sizes, int n_in,
                              void* d_out, int out_size, void* d_ws, size_t ws_size,
                              hipStream_t stream) {
    const float*         h      = (const float*)d_in[0];
    const unsigned char* exited = (const unsigned char*)d_in[1]; // all-false in bench; byte view is size-safe
    const float*         W      = (const float*)d_in[2];
    const float*         bias   = (const float*)d_in[3];

    float* scores = (float*)d_out;            // output 0: (B,T,1) f32
    float* maskp  = scores + (size_t)B_ * T_; // output 1: (B,T,1) as 0/1 f32

    // keys scratch: use d_ws if big enough, else stage in the mask region
    // (kernel 2 reads keys into registers before overwriting with the mask).
    uint32_t* keys = (ws_size >= sizeof(uint32_t) * (size_t)B_ * T_)
                         ? (uint32_t*)d_ws
                         : (uint32_t*)maskp;

    score_kernel<<<(B_ * T_) / 4, 256, 0, stream>>>(h, W, bias, scores, keys);
    topk_kernel<<<B_, 1024, 0, stream>>>(keys, scores, exited, maskp);
}

// Round 2
// 363.558 us; speedup vs baseline: 1.0526x; 1.0526x over previous
//
#include <hip/hip_runtime.h>
#include <cstdint>
#include <cstddef>

#define B_ 4
#define T_ 8192
#define D_ 2048
#define K_ 4096   // int(0.5*T + 0.5) = 4096

// ---------------- Kernel 1: scores + sortable keys -------------------------
// One wave handles TWO consecutive rows (16 dwordx4 loads in flight/lane).
// block = 256 threads = 4 waves = 8 rows; grid = 32768/8 = 4096 blocks.
__global__ __launch_bounds__(256) void score_kernel(
    const float* __restrict__ h, const float* __restrict__ W,
    const float* __restrict__ bias, float* __restrict__ scores,
    uint32_t* __restrict__ keys)
{
    __shared__ float4 wlds[D_ / 4];
    const int tid = threadIdx.x;
    const float4* W4 = (const float4*)W;
    #pragma unroll
    for (int i = 0; i < (D_ / 4) / 256; ++i)
        wlds[tid + i * 256] = W4[tid + i * 256];
    __syncthreads();

    const int lane = tid & 63;
    const int wid  = tid >> 6;
    const int row  = blockIdx.x * 8 + wid * 2;

    const float4* hA = (const float4*)(h + (size_t)row * D_);
    const float4* hB = (const float4*)(h + (size_t)(row + 1) * D_);
    float acc0 = 0.f, acc1 = 0.f;
    #pragma unroll
    for (int j = 0; j < 8; ++j) {
        float4 a = hA[lane + j * 64];
        float4 c = hB[lane + j * 64];
        float4 w = wlds[lane + j * 64];
        acc0 = fmaf(a.x, w.x, acc0);
        acc0 = fmaf(a.y, w.y, acc0);
        acc0 = fmaf(a.z, w.z, acc0);
        acc0 = fmaf(a.w, w.w, acc0);
        acc1 = fmaf(c.x, w.x, acc1);
        acc1 = fmaf(c.y, w.y, acc1);
        acc1 = fmaf(c.z, w.z, acc1);
        acc1 = fmaf(c.w, w.w, acc1);
    }
    #pragma unroll
    for (int off = 32; off > 0; off >>= 1) {
        acc0 += __shfl_down(acc0, off);
        acc1 += __shfl_down(acc1, off);
    }

    if (lane == 0) {
        const float zb = bias[0];
        float z0 = acc0 + zb;
        float z1 = acc1 + zb;
        scores[row]     = 1.0f / (1.0f + expf(-z0));
        scores[row + 1] = 1.0f / (1.0f + expf(-z1));
        uint32_t u0 = __float_as_uint(z0);
        uint32_t u1 = __float_as_uint(z1);
        keys[row]     = (u0 & 0x80000000u) ? ~u0 : (u0 | 0x80000000u);
        keys[row + 1] = (u1 & 0x80000000u) ? ~u1 : (u1 | 0x80000000u);
    }
}

// ---------------- Kernel 2: exact k-th largest via 4-level radix select ----
// One block (1024 threads) per batch row; 8 keys/thread in registers
// (thread t owns contiguous [t*8, t*8+8) -> stable tie ranking by index).
// 3 barriers/level x 4 levels + 3 for tie-scan, vs ~100 for binary search.
__global__ __launch_bounds__(1024) void topk_kernel(
    const uint32_t* __restrict__ keys, const float* __restrict__ scores,
    const unsigned char* __restrict__ exited, float* __restrict__ mask)
{
    const int b    = blockIdx.x;
    const int tid  = threadIdx.x;
    const int lane = tid & 63;
    const int wid  = tid >> 6;

    __shared__ int hist[256];
    __shared__ int lvl_bin;   // selected bucket at this level
    __shared__ int lvl_cab;   // count of matching keys with byte > bucket
    __shared__ int red[16];

    const uint32_t* krow = keys + (size_t)b * T_;
    uint32_t key[8];
    {
        const uint4* k4 = (const uint4*)(krow + tid * 8);
        uint4 ka = k4[0], kb = k4[1];
        key[0] = ka.x; key[1] = ka.y; key[2] = ka.z; key[3] = ka.w;
        key[4] = kb.x; key[5] = kb.y; key[6] = kb.z; key[7] = kb.w;
    }

    uint32_t prefix   = 0u;   // determined high bytes of Kstar
    uint32_t prefmask = 0u;   // which bytes are determined
    int k = K_;               // rank still to satisfy among matching keys
    int cgt = 0;              // total count of keys strictly > Kstar

    for (int level = 0; level < 4; ++level) {
        const int shift = 24 - 8 * level;
        if (tid < 256) hist[tid] = 0;
        __syncthreads();                                   // (A) zero visible
        #pragma unroll
        for (int j = 0; j < 8; ++j) {
            if ((key[j] & prefmask) == prefix)
                atomicAdd(&hist[(key[j] >> shift) & 0xFF], 1);
        }
        __syncthreads();                                   // (B) hist complete
        if (wid == 0) {
            // lane owns bins [4*lane, 4*lane+3]; suffix-scan from top bin down
            int4 hv = ((const int4*)hist)[lane];
            int s = hv.x + hv.y + hv.z + hv.w;
            int suf = s;                                   // inclusive suffix sum
            #pragma unroll
            for (int off = 1; off < 64; off <<= 1) {
                int y = __shfl_down(suf, off);
                if (lane + off < 64) suf += y;
            }
            const int above = suf - s;                     // sum over lanes > lane
            const int cab3 = above;
            const int cab2 = above + hv.w;
            const int cab1 = above + hv.w + hv.z;
            const int cab0 = above + hv.w + hv.z + hv.y;
            // exactly one (bin, h>0) satisfies cab < k <= cab + h
            if      (cab3 < k && k <= cab3 + hv.w) { lvl_bin = 4*lane+3; lvl_cab = cab3; }
            else if (cab2 < k && k <= cab2 + hv.z) { lvl_bin = 4*lane+2; lvl_cab = cab2; }
            else if (cab1 < k && k <= cab1 + hv.y) { lvl_bin = 4*lane+1; lvl_cab = cab1; }
            else if (cab0 < k && k <= cab0 + hv.x) { lvl_bin = 4*lane+0; lvl_cab = cab0; }
        }
        __syncthreads();                                   // (C) lvl_* ready
        const int bsel = lvl_bin;
        const int cab  = lvl_cab;
        cgt += cab;
        k   -= cab;
        prefix   |= ((uint32_t)bsel) << shift;
        prefmask |= 0xFFu << shift;
        // next iteration's (B) orders these reads before the next lvl_* write;
        // hist zeroing happens after (C) while wave0 reads were pre-(C). safe.
    }
    const uint32_t Kstar  = prefix;
    const int      budget = K_ - cgt;      // # ties (== Kstar) to accept

    // stable tie ranking: exclusive prefix (by index) of (key == Kstar)
    int tieLocal = 0;
    #pragma unroll
    for (int j = 0; j < 8; ++j) tieLocal += (key[j] == Kstar) ? 1 : 0;
    int inc = tieLocal;
    #pragma unroll
    for (int off = 1; off < 64; off <<= 1) {
        int y = __shfl_up(inc, off);
        if (lane >= off) inc += y;
    }
    if (lane == 63) red[wid] = inc;        // wave totals
    __syncthreads();
    if (tid == 0) {
        int run = 0;
        for (int i = 0; i < 16; ++i) { int t = red[i]; red[i] = run; run += t; }
    }
    __syncthreads();
    int tieOff = red[wid] + (inc - tieLocal);   // my exclusive tie rank

    const float*         srow = scores + (size_t)b * T_;
    const unsigned char* erow = exited + (size_t)b * T_;
    float4 s4a = ((const float4*)(srow + tid * 8))[0];
    float4 s4b = ((const float4*)(srow + tid * 8))[1];
    const float sv[8] = {s4a.x, s4a.y, s4a.z, s4a.w, s4b.x, s4b.y, s4b.z, s4b.w};
    unsigned long long e8 = ((const unsigned long long*)(erow + tid * 8))[0];

    float out[8];
    #pragma unroll
    for (int j = 0; j < 8; ++j) {
        bool sel;
        if (key[j] > Kstar)       sel = true;
        else if (key[j] == Kstar) { sel = (tieOff < budget); ++tieOff; }
        else                      sel = false;
        const bool ex = ((e8 >> (8 * j)) & 0xFFull) != 0ull;
        sel = sel && (sv[j] > 0.5f) && !ex;
        out[j] = sel ? 1.0f : 0.0f;
    }
    float4* m4 = (float4*)(mask + (size_t)b * T_ + tid * 8);
    m4[0] = make_float4(out[0], out[1], out[2], out[3]);
    m4[1] = make_float4(out[4], out[5], out[6], out[7]);
}

// ---------------------------------------------------------------------------
extern "C" void kernel_launch(void* const* d_in, const int* in_sizes, int n_in,
                              void* d_out, int out_size, void* d_ws, size_t ws_size,
                              hipStream_t stream) {
    const float*         h      = (const float*)d_in[0];
    const unsigned char* exited = (const unsigned char*)d_in[1];
    const float*         W      = (const float*)d_in[2];
    const float*         bias   = (const float*)d_in[3];

    float* scores = (float*)d_out;            // output 0: (B,T,1) f32
    float* maskp  = scores + (size_t)B_ * T_; // output 1: (B,T,1) as 0/1 f32

    uint32_t* keys = (ws_size >= sizeof(uint32_t) * (size_t)B_ * T_)
                         ? (uint32_t*)d_ws
                         : (uint32_t*)maskp;  // fallback: staged then overwritten

    score_kernel<<<(B_ * T_) / 8, 256, 0, stream>>>(h, W, bias, scores, keys);
    topk_kernel<<<B_, 1024, 0, stream>>>(keys, scores, exited, maskp);
}

// Round 3
// 360.624 us; speedup vs baseline: 1.0611x; 1.0081x over previous
//
#include <hip/hip_runtime.h>
#include <cstdint>
#include <cstddef>

#define B_ 4
#define T_ 8192
#define D_ 2048
#define K_ 4096   // int(0.5*T + 0.5) = 4096

// ---------------- Kernel 1: scores + sortable keys -------------------------
// One wave handles TWO consecutive rows. W fragment kept in registers
// (8 float4/lane, same per-(lane,j) values as the LDS version -> bit-identical
// accumulation order). No LDS, no __syncthreads.
// block = 256 threads = 4 waves = 8 rows; grid = 32768/8 = 4096 blocks.
__global__ __launch_bounds__(256) void score_kernel(
    const float* __restrict__ h, const float* __restrict__ W,
    const float* __restrict__ bias, float* __restrict__ scores,
    uint32_t* __restrict__ keys)
{
    const int tid  = threadIdx.x;
    const int lane = tid & 63;
    const int wid  = tid >> 6;
    const int row  = blockIdx.x * 8 + wid * 2;

    const float4* W4 = (const float4*)W;
    const float4* hA = (const float4*)(h + (size_t)row * D_);
    const float4* hB = (const float4*)(h + (size_t)(row + 1) * D_);

    // issue all 24 loads (8 W + 16 h) before any FMA
    float4 w[8], a[8], c[8];
    #pragma unroll
    for (int j = 0; j < 8; ++j) w[j] = W4[lane + j * 64];
    #pragma unroll
    for (int j = 0; j < 8; ++j) a[j] = hA[lane + j * 64];
    #pragma unroll
    for (int j = 0; j < 8; ++j) c[j] = hB[lane + j * 64];

    float acc0 = 0.f, acc1 = 0.f;
    #pragma unroll
    for (int j = 0; j < 8; ++j) {
        acc0 = fmaf(a[j].x, w[j].x, acc0);
        acc0 = fmaf(a[j].y, w[j].y, acc0);
        acc0 = fmaf(a[j].z, w[j].z, acc0);
        acc0 = fmaf(a[j].w, w[j].w, acc0);
        acc1 = fmaf(c[j].x, w[j].x, acc1);
        acc1 = fmaf(c[j].y, w[j].y, acc1);
        acc1 = fmaf(c[j].z, w[j].z, acc1);
        acc1 = fmaf(c[j].w, w[j].w, acc1);
    }
    #pragma unroll
    for (int off = 32; off > 0; off >>= 1) {
        acc0 += __shfl_down(acc0, off);
        acc1 += __shfl_down(acc1, off);
    }

    if (lane == 0) {
        const float zb = bias[0];
        float z0 = acc0 + zb;
        float z1 = acc1 + zb;
        scores[row]     = 1.0f / (1.0f + expf(-z0));
        scores[row + 1] = 1.0f / (1.0f + expf(-z1));
        uint32_t u0 = __float_as_uint(z0);
        uint32_t u1 = __float_as_uint(z1);
        keys[row]     = (u0 & 0x80000000u) ? ~u0 : (u0 | 0x80000000u);
        keys[row + 1] = (u1 & 0x80000000u) ? ~u1 : (u1 | 0x80000000u);
    }
}

// ---------------- Kernel 2: exact k-th largest via 4-level radix select ----
// One block (1024 threads) per batch row; 8 keys/thread in registers
// (thread t owns contiguous [t*8, t*8+8) -> stable tie ranking by index).
__global__ __launch_bounds__(1024) void topk_kernel(
    const uint32_t* __restrict__ keys, const float* __restrict__ scores,
    const unsigned char* __restrict__ exited, float* __restrict__ mask)
{
    const int b    = blockIdx.x;
    const int tid  = threadIdx.x;
    const int lane = tid & 63;
    const int wid  = tid >> 6;

    __shared__ int hist[256];
    __shared__ int lvl_bin;
    __shared__ int lvl_cab;
    __shared__ int red[16];

    const uint32_t* krow = keys + (size_t)b * T_;
    uint32_t key[8];
    {
        const uint4* k4 = (const uint4*)(krow + tid * 8);
        uint4 ka = k4[0], kb = k4[1];
        key[0] = ka.x; key[1] = ka.y; key[2] = ka.z; key[3] = ka.w;
        key[4] = kb.x; key[5] = kb.y; key[6] = kb.z; key[7] = kb.w;
    }

    uint32_t prefix   = 0u;
    uint32_t prefmask = 0u;
    int k = K_;
    int cgt = 0;

    for (int level = 0; level < 4; ++level) {
        const int shift = 24 - 8 * level;
        if (tid < 256) hist[tid] = 0;
        __syncthreads();                                   // (A) zero visible
        #pragma unroll
        for (int j = 0; j < 8; ++j) {
            if ((key[j] & prefmask) == prefix)
                atomicAdd(&hist[(key[j] >> shift) & 0xFF], 1);
        }
        __syncthreads();                                   // (B) hist complete
        if (wid == 0) {
            int4 hv = ((const int4*)hist)[lane];
            int s = hv.x + hv.y + hv.z + hv.w;
            int suf = s;
            #pragma unroll
            for (int off = 1; off < 64; off <<= 1) {
                int y = __shfl_down(suf, off);
                if (lane + off < 64) suf += y;
            }
            const int above = suf - s;
            const int cab3 = above;
            const int cab2 = above + hv.w;
            const int cab1 = above + hv.w + hv.z;
            const int cab0 = above + hv.w + hv.z + hv.y;
            if      (cab3 < k && k <= cab3 + hv.w) { lvl_bin = 4*lane+3; lvl_cab = cab3; }
            else if (cab2 < k && k <= cab2 + hv.z) { lvl_bin = 4*lane+2; lvl_cab = cab2; }
            else if (cab1 < k && k <= cab1 + hv.y) { lvl_bin = 4*lane+1; lvl_cab = cab1; }
            else if (cab0 < k && k <= cab0 + hv.x) { lvl_bin = 4*lane+0; lvl_cab = cab0; }
        }
        __syncthreads();                                   // (C) lvl_* ready
        const int bsel = lvl_bin;
        const int cab  = lvl_cab;
        cgt += cab;
        k   -= cab;
        prefix   |= ((uint32_t)bsel) << shift;
        prefmask |= 0xFFu << shift;
    }
    const uint32_t Kstar  = prefix;
    const int      budget = K_ - cgt;

    int tieLocal = 0;
    #pragma unroll
    for (int j = 0; j < 8; ++j) tieLocal += (key[j] == Kstar) ? 1 : 0;
    int inc = tieLocal;
    #pragma unroll
    for (int off = 1; off < 64; off <<= 1) {
        int y = __shfl_up(inc, off);
        if (lane >= off) inc += y;
    }
    if (lane == 63) red[wid] = inc;
    __syncthreads();
    if (tid == 0) {
        int run = 0;
        for (int i = 0; i < 16; ++i) { int t = red[i]; red[i] = run; run += t; }
    }
    __syncthreads();
    int tieOff = red[wid] + (inc - tieLocal);

    const float*         srow = scores + (size_t)b * T_;
    const unsigned char* erow = exited + (size_t)b * T_;
    float4 s4a = ((const float4*)(srow + tid * 8))[0];
    float4 s4b = ((const float4*)(srow + tid * 8))[1];
    const float sv[8] = {s4a.x, s4a.y, s4a.z, s4a.w, s4b.x, s4b.y, s4b.z, s4b.w};
    unsigned long long e8 = ((const unsigned long long*)(erow + tid * 8))[0];

    float out[8];
    #pragma unroll
    for (int j = 0; j < 8; ++j) {
        bool sel;
        if (key[j] > Kstar)       sel = true;
        else if (key[j] == Kstar) { sel = (tieOff < budget); ++tieOff; }
        else                      sel = false;
        const bool ex = ((e8 >> (8 * j)) & 0xFFull) != 0ull;
        sel = sel && (sv[j] > 0.5f) && !ex;
        out[j] = sel ? 1.0f : 0.0f;
    }
    float4* m4 = (float4*)(mask + (size_t)b * T_ + tid * 8);
    m4[0] = make_float4(out[0], out[1], out[2], out[3]);
    m4[1] = make_float4(out[4], out[5], out[6], out[7]);
}

// ---------------------------------------------------------------------------
extern "C" void kernel_launch(void* const* d_in, const int* in_sizes, int n_in,
                              void* d_out, int out_size, void* d_ws, size_t ws_size,
                              hipStream_t stream) {
    const float*         h      = (const float*)d_in[0];
    const unsigned char* exited = (const unsigned char*)d_in[1];
    const float*         W      = (const float*)d_in[2];
    const float*         bias   = (const float*)d_in[3];

    float* scores = (float*)d_out;            // output 0: (B,T,1) f32
    float* maskp  = scores + (size_t)B_ * T_; // output 1: (B,T,1) as 0/1 f32

    uint32_t* keys = (ws_size >= sizeof(uint32_t) * (size_t)B_ * T_)
                         ? (uint32_t*)d_ws
                         : (uint32_t*)maskp;

    score_kernel<<<(B_ * T_) / 8, 256, 0, stream>>>(h, W, bias, scores, keys);
    topk_kernel<<<B_, 1024, 0, stream>>>(keys, scores, exited, maskp);
}